// Round 3
// baseline (299.600 us; speedup 1.0000x reference)
//
#include <hip/hip_runtime.h>
#include <hip/hip_bf16.h>
#include <cstdint>
#include <cstddef>

// Problem constants
#define NB 512
#define NR 1152
#define NC 8
#define NJ 10
#define NO 16
#define NJO 160   // NJ*NO

typedef unsigned int uint32;

// ---- bf16 helpers (RNE pack, bit-shift unpack) ----
__device__ __forceinline__ uint32 f2bf(float f) {
    uint32 x = __float_as_uint(f);
    return (x + 0x7fffu + ((x >> 16) & 1u)) >> 16;
}
__device__ __forceinline__ float bflo(uint32 w) { return __uint_as_float(w << 16); }
__device__ __forceinline__ float bfhi(uint32 w) { return __uint_as_float(w & 0xffff0000u); }

// k must be a compile-time-foldable expression (fully unrolled loops only)
#define UVAL(k) (((k) & 1) ? bfhi(u32[(k) >> 1]) : bflo(u32[(k) >> 1]))

// ============================================================================
// Kernel 0: transpose x[b][r][c] -> xT[r][b][c] so uhat can stage x coalesced.
// Tile 64 b x 16 r, float4 both sides via LDS.
// ============================================================================
__global__ __launch_bounds__(256) void xpose_kernel(const float* __restrict__ x,
                                                    float* __restrict__ xT) {
    const int r0 = blockIdx.x * 16;
    const int b0 = blockIdx.y * 64;
    const int t  = threadIdx.x;
    __shared__ float tile[16][65][8];  // row stride 520 floats (16B-aligned, breaks pow2)

    // read: 2048 float4s; lanes cover contiguous 512B per b-row
    for (int i = t; i < 2048; i += 256) {
        int b = i >> 5, r = (i >> 1) & 15, h = i & 1;
        float4 v = *(const float4*)&x[(size_t)(b0 + b) * (NR * NC) + (size_t)(r0 + r) * NC + h * 4];
        *(float4*)&tile[r][b][h * 4] = v;
    }
    __syncthreads();
    // write: contiguous 2KB per r-row
    for (int i = t; i < 2048; i += 256) {
        int r = i >> 7, b = (i >> 1) & 63, h = i & 1;
        float4 v = *(const float4*)&tile[r][b][h * 4];
        *(float4*)&xT[(size_t)(r0 + r) * (NB * NC) + (size_t)(b0 + b) * NC + h * 4] = v;
    }
}

// ============================================================================
// Kernel 1: u_hat[b,r,j,o] = sum_c W[r,j,o,c] * xT[r,b,c], stored bf16.
// One block per r. W[r] (5KB) -> LDS transposed [c][jo]; xT[r] (16KB) -> LDS
// (now a single contiguous 16KB float4 copy).
// ============================================================================
__global__ __launch_bounds__(320) void uhat_kernel(const float* __restrict__ xT,
                                                   const float* __restrict__ W,
                                                   uint32* __restrict__ u /* packed bf16 pairs */) {
    const int r = blockIdx.x;
    const int t = threadIdx.x;

    __shared__ float Ws[NC][NJO];   // 5 KB, transposed: [c][jo]
    __shared__ float xs[NB][NC];    // 16 KB

    for (int i = t; i < NJO * NC; i += 320) {
        Ws[i & 7][i >> 3] = W[(size_t)r * (NJO * NC) + i];
    }
    {
        const float4* xsrc = (const float4*)(xT + (size_t)r * (NB * NC));
        float4* xdst = (float4*)&xs[0][0];
        for (int i = t; i < (NB * NC) / 4; i += 320) xdst[i] = xsrc[i];
    }
    __syncthreads();

    const int jo2  = t % 80;   // pair index: handles jo = 2*jo2, 2*jo2+1
    const int half = t / 80;   // 0..3

    float w0[8], w1[8];
#pragma unroll
    for (int c = 0; c < 8; ++c) {
        w0[c] = Ws[c][2 * jo2];
        w1[c] = Ws[c][2 * jo2 + 1];
    }

    for (int b = half; b < NB; b += 4) {
        const float4* xp = (const float4*)xs[b];
        float4 xa = xp[0], xb = xp[1];
        float a0 = w0[0] * xa.x + w0[1] * xa.y + w0[2] * xa.z + w0[3] * xa.w
                 + w0[4] * xb.x + w0[5] * xb.y + w0[6] * xb.z + w0[7] * xb.w;
        float a1 = w1[0] * xa.x + w1[1] * xa.y + w1[2] * xa.z + w1[3] * xa.w
                 + w1[4] * xb.x + w1[5] * xb.y + w1[6] * xb.z + w1[7] * xb.w;
        uint32 p = f2bf(a0) | (f2bf(a1) << 16);
        u[(size_t)(b * NR + r) * 80 + jo2] = p;
    }
}

// ============================================================================
// Routing pass kernel. 6 waves per block; one thread per (b, r).
// Grid = (3, B), block = 384. Each wave reduce-scatters its 64 r's:
// 6 xor stages (96+48+24+12+6+3 = 189 shuffles); lane l ends owning the
// complete wave-sums for jo = 3*bitrev6(l) + {0,1,2}; one global atomicAdd
// each (18 waves per b).
// ============================================================================
template <bool UNIFORM>
__global__ __launch_bounds__(384) void pass_kernel(const uint32* __restrict__ u,
                                                   const float* __restrict__ vsum,
                                                   float* __restrict__ s) {
    const int b    = blockIdx.y;
    const int t    = threadIdx.x;
    const int lane = t & 63;
    const int r    = blockIdx.x * 384 + t;

    __shared__ float vs[NJO];
    if (!UNIFORM) {
        if (t < NJO) vs[t] = vsum[b * NJO + t];
        __syncthreads();
    }

    // load this (b,r)'s 160 bf16 u values: 20 x dwordx4, fully coalesced
    uint32 u32[80];
    const uint4* up = (const uint4*)(u + (size_t)(b * NR + r) * 80);
#pragma unroll
    for (int i = 0; i < 20; ++i) {
        uint4 q = up[i];
        u32[4 * i + 0] = q.x;
        u32[4 * i + 1] = q.y;
        u32[4 * i + 2] = q.z;
        u32[4 * i + 3] = q.w;
    }

    float cj[NJ];
    if (UNIFORM) {
#pragma unroll
        for (int j = 0; j < NJ; ++j) cj[j] = 1.0f / NJ;
    } else {
        float bj[NJ];
        const float4* vp = (const float4*)vs;
#pragma unroll
        for (int j = 0; j < NJ; ++j) {
            float acc = 0.0f;
#pragma unroll
            for (int q = 0; q < 4; ++q) {
                float4 v4 = vp[j * 4 + q];
                acc += v4.x * UVAL(j * 16 + q * 4 + 0);
                acc += v4.y * UVAL(j * 16 + q * 4 + 1);
                acc += v4.z * UVAL(j * 16 + q * 4 + 2);
                acc += v4.w * UVAL(j * 16 + q * 4 + 3);
            }
            bj[j] = acc;
        }
        float m = bj[0];
#pragma unroll
        for (int j = 1; j < NJ; ++j) m = fmaxf(m, bj[j]);
        float sum = 0.0f;
#pragma unroll
        for (int j = 0; j < NJ; ++j) {
            float e = __expf(bj[j] - m);
            cj[j] = e;
            sum += e;
        }
        float inv = 1.0f / sum;
#pragma unroll
        for (int j = 0; j < NJ; ++j) cj[j] *= inv;
    }

    // contribution k (k in [0,192), padded past 160 with zeros)
    auto contrib = [&](int k) -> float {
        if (k >= NJO) return 0.0f;
        return cj[k >> 4] * UVAL(k);
    };

    // ---- reduce-scatter over the 64 lanes of this wave ----
    float a[96];
    {
        const int bit = lane & 1;
#pragma unroll
        for (int i = 0; i < 96; ++i) {
            float lo = contrib(i);
            float hi = contrib(i + 96);
            float send = bit ? lo : hi;
            float recv = __shfl_xor(send, 1);
            a[i] = (bit ? hi : lo) + recv;
        }
    }
#pragma unroll
    for (int st = 1; st < 6; ++st) {
        const int h = 96 >> st;              // 48,24,12,6,3
        const int bit = (lane >> st) & 1;
#pragma unroll
        for (int i = 0; i < 48; ++i) {
            if (i < h) {
                float send = bit ? a[i] : a[i + h];
                float recv = __shfl_xor(send, 1 << st);
                a[i] = (bit ? a[i + h] : a[i]) + recv;
            }
        }
    }

    // lane owns jo = 3*bitrev6(lane) + {0,1,2}
    const int base = 3 * (__brev((uint32)lane) >> 26);
#pragma unroll
    for (int i = 0; i < 3; ++i) {
        int jo = base + i;
        if (jo < NJO) atomicAdd(&s[b * NJO + jo], a[i]);
    }
}

// ============================================================================
// Squash: per (b,j): sq = sum_o s^2; v = (sq/(1+sq)) * s * rsqrt(sq + 1e-8).
// FINAL=false: vacc += v (running vsum). FINAL=true: write v to out.
// ============================================================================
template <bool FINAL>
__global__ __launch_bounds__(256) void squash_kernel(const float* __restrict__ s,
                                                     float* __restrict__ vacc) {
    const int idx = blockIdx.x * 256 + threadIdx.x;  // < 81920
    float val = s[idx];
    float sq = val * val;
#pragma unroll
    for (int off = 1; off < 16; off <<= 1) sq += __shfl_xor(sq, off, 16);
    float scale = (sq / (1.0f + sq)) * rsqrtf(sq + 1e-8f);
    float v = val * scale;
    if (FINAL) vacc[idx] = v;
    else       vacc[idx] += v;
}

// ============================================================================
extern "C" void kernel_launch(void* const* d_in, const int* in_sizes, int n_in,
                              void* d_out, int out_size, void* d_ws, size_t ws_size,
                              hipStream_t stream) {
    (void)in_sizes; (void)n_in; (void)out_size; (void)ws_size;

    const float* x = (const float*)d_in[0];  // [B,R,C]
    const float* W = (const float*)d_in[1];  // [R,J,O,C]
    float* out = (float*)d_out;              // [B,J,O,1] fp32

    char* ws = (char*)d_ws;
    const size_t XBYTES = (size_t)NR * NB * NC * 4;   // 18,874,368 (xT fp32)
    const size_t UBYTES = (size_t)NB * NR * NJO * 2;  // 188,743,680 (bf16 u_hat)
    float*  xT  = (float*)ws;
    uint32* u   = (uint32*)(ws + XBYTES);
    float* s0   = (float*)(ws + XBYTES + UBYTES);
    float* s1   = s0 + NB * NJO;
    float* s2   = s1 + NB * NJO;
    float* vsum = s2 + NB * NJO;

    // zero s0,s1,s2,vsum (contiguous)
    hipMemsetAsync(s0, 0, (size_t)4 * NB * NJO * sizeof(float), stream);

    // transpose x for coalesced uhat staging
    xpose_kernel<<<dim3(NR / 16, NB / 64), 256, 0, stream>>>(x, xT);

    // u_hat
    uhat_kernel<<<NR, 320, 0, stream>>>(xT, W, u);

    // iter 0: c uniform -> s0 -> v0 (vsum = v0)
    pass_kernel<true><<<dim3(3, NB), 384, 0, stream>>>(u, nullptr, s0);
    squash_kernel<false><<<(NB * NJO) / 256, 256, 0, stream>>>(s0, vsum);

    // iter 1: b1 = u.v0 -> c1 -> s1 -> v1 (vsum = v0+v1)
    pass_kernel<false><<<dim3(3, NB), 384, 0, stream>>>(u, vsum, s1);
    squash_kernel<false><<<(NB * NJO) / 256, 256, 0, stream>>>(s1, vsum);

    // iter 2: b2 = u.(v0+v1) -> c2 -> s2 -> v2 = output
    pass_kernel<false><<<dim3(3, NB), 384, 0, stream>>>(u, vsum, s2);
    squash_kernel<true><<<(NB * NJO) / 256, 256, 0, stream>>>(s2, out);
}

// Round 4
// 240.361 us; speedup vs baseline: 1.2465x; 1.2465x over previous
//
#include <hip/hip_runtime.h>
#include <hip/hip_bf16.h>
#include <cstdint>
#include <cstddef>

// Problem constants
#define NB 512
#define NR 1152
#define NC 8
#define NJ 10
#define NO 16
#define NJO 160   // NJ*NO

typedef unsigned int uint32;

// ---- bf16 helpers (RNE pack, bit-shift unpack) ----
__device__ __forceinline__ uint32 f2bf(float f) {
    uint32 x = __float_as_uint(f);
    return (x + 0x7fffu + ((x >> 16) & 1u)) >> 16;
}
__device__ __forceinline__ float bflo(uint32 w) { return __uint_as_float(w << 16); }
__device__ __forceinline__ float bfhi(uint32 w) { return __uint_as_float(w & 0xffff0000u); }

// ============================================================================
// Kernel 0: transpose x[b][r][c] -> xT[r][b][c] so uhat can stage x coalesced.
// ============================================================================
__global__ __launch_bounds__(256) void xpose_kernel(const float* __restrict__ x,
                                                    float* __restrict__ xT) {
    const int r0 = blockIdx.x * 16;
    const int b0 = blockIdx.y * 64;
    const int t  = threadIdx.x;
    __shared__ float tile[16][65][8];

    for (int i = t; i < 2048; i += 256) {
        int b = i >> 5, r = (i >> 1) & 15, h = i & 1;
        float4 v = *(const float4*)&x[(size_t)(b0 + b) * (NR * NC) + (size_t)(r0 + r) * NC + h * 4];
        *(float4*)&tile[r][b][h * 4] = v;
    }
    __syncthreads();
    for (int i = t; i < 2048; i += 256) {
        int r = i >> 7, b = (i >> 1) & 63, h = i & 1;
        float4 v = *(const float4*)&tile[r][b][h * 4];
        *(float4*)&xT[(size_t)(r0 + r) * (NB * NC) + (size_t)(b0 + b) * NC + h * 4] = v;
    }
}

// ============================================================================
// Kernel 1: u_hat[b,r,j,o] = sum_c W[r,j,o,c] * xT[r,b,c], stored bf16 pairs.
// ============================================================================
__global__ __launch_bounds__(320) void uhat_kernel(const float* __restrict__ xT,
                                                   const float* __restrict__ W,
                                                   uint32* __restrict__ u) {
    const int r = blockIdx.x;
    const int t = threadIdx.x;

    __shared__ float Ws[NC][NJO];   // 5 KB transposed [c][jo]
    __shared__ float xs[NB][NC];    // 16 KB

    for (int i = t; i < NJO * NC; i += 320) {
        Ws[i & 7][i >> 3] = W[(size_t)r * (NJO * NC) + i];
    }
    {
        const float4* xsrc = (const float4*)(xT + (size_t)r * (NB * NC));
        float4* xdst = (float4*)&xs[0][0];
        for (int i = t; i < (NB * NC) / 4; i += 320) xdst[i] = xsrc[i];
    }
    __syncthreads();

    const int jo2  = t % 80;
    const int half = t / 80;

    float w0[8], w1[8];
#pragma unroll
    for (int c = 0; c < 8; ++c) {
        w0[c] = Ws[c][2 * jo2];
        w1[c] = Ws[c][2 * jo2 + 1];
    }

    for (int b = half; b < NB; b += 4) {
        const float4* xp = (const float4*)xs[b];
        float4 xa = xp[0], xb = xp[1];
        float a0 = w0[0] * xa.x + w0[1] * xa.y + w0[2] * xa.z + w0[3] * xa.w
                 + w0[4] * xb.x + w0[5] * xb.y + w0[6] * xb.z + w0[7] * xb.w;
        float a1 = w1[0] * xa.x + w1[1] * xa.y + w1[2] * xa.z + w1[3] * xa.w
                 + w1[4] * xb.x + w1[5] * xb.y + w1[6] * xb.z + w1[7] * xb.w;
        uint32 p = f2bf(a0) | (f2bf(a1) << 16);
        u[(size_t)(b * NR + r) * 80 + jo2] = p;
    }
}

// ============================================================================
// Fused routing pass + squash. ONE BLOCK PER b (128 threads = 2 waves).
// Each wave handles 576 r's in 9 chunks of 64 (one r per lane per chunk):
//   - b_ij = u . vsum_bf16 (vs held in 80 u32 registers), softmax (no max-sub:
//     |b_ij| <~ 40 so exp is safe in fp32)
//   - acc[jo] += c_j * u[jo]  -- 160 fp32 registers, amortizing the butterfly
// After the chunk loop: ONE butterfly reduce-scatter (189 shuffles per wave
// instead of per 64 r's), 3 owned jo per lane -> LDS tile (2-way ds_add),
// then in-block squash; non-final passes update fp32 vacc and emit bf16-packed
// vsum for the next pass.
// ============================================================================
template <bool UNIFORM, bool FINAL>
__global__ __launch_bounds__(128, 1) void pass_kernel(const uint32* __restrict__ u,
                                                      const uint32* __restrict__ vsb,
                                                      float* __restrict__ vacc,
                                                      float* __restrict__ outp) {
    const int b    = blockIdx.x;
    const int t    = threadIdx.x;
    const int wv   = t >> 6;
    const int lane = t & 63;

    __shared__ float sl[NJO];
    for (int i = t; i < NJO; i += 128) sl[i] = 0.0f;
    __syncthreads();

    // vsum (bf16-packed) in registers: 80 u32
    uint32 vs[80];
    if (!UNIFORM) {
        const uint4* vp = (const uint4*)(vsb + b * 80);
#pragma unroll
        for (int i = 0; i < 20; ++i) {
            uint4 q = vp[i];
            vs[4 * i + 0] = q.x; vs[4 * i + 1] = q.y;
            vs[4 * i + 2] = q.z; vs[4 * i + 3] = q.w;
        }
    }

    float acc[NJO];
#pragma unroll
    for (int i = 0; i < NJO; ++i) acc[i] = 0.0f;

#pragma unroll 1
    for (int c = 0; c < 9; ++c) {
        const int r = wv * 576 + c * 64 + lane;
        uint32 ur[80];
        const uint4* up = (const uint4*)(u + ((size_t)b * NR + r) * 80);
#pragma unroll
        for (int i = 0; i < 20; ++i) {
            uint4 q = up[i];
            ur[4 * i + 0] = q.x; ur[4 * i + 1] = q.y;
            ur[4 * i + 2] = q.z; ur[4 * i + 3] = q.w;
        }

        float cj[NJ];
        if (UNIFORM) {
#pragma unroll
            for (int j = 0; j < NJ; ++j) cj[j] = 0.1f;
        } else {
            float sum = 0.0f;
#pragma unroll
            for (int j = 0; j < NJ; ++j) {
                float bj = 0.0f;
#pragma unroll
                for (int q = 0; q < 8; ++q) {
                    uint32 uu = ur[8 * j + q], vv = vs[8 * j + q];
                    bj += bflo(uu) * bflo(vv) + bfhi(uu) * bfhi(vv);
                }
                float e = __expf(bj);   // |bj| bounded ~40: no max-subtract needed
                cj[j] = e;
                sum += e;
            }
            float inv = 1.0f / sum;
#pragma unroll
            for (int j = 0; j < NJ; ++j) cj[j] *= inv;
        }

#pragma unroll
        for (int j = 0; j < NJ; ++j) {
#pragma unroll
            for (int q = 0; q < 8; ++q) {
                uint32 uu = ur[8 * j + q];
                acc[16 * j + 2 * q]     += cj[j] * bflo(uu);
                acc[16 * j + 2 * q + 1] += cj[j] * bfhi(uu);
            }
        }
    }

    // ---- ONE butterfly reduce-scatter per wave (pad 160 -> 192 implicit) ----
    float a[96];
    {
        const int bit = lane & 1;
#pragma unroll
        for (int i = 0; i < 96; ++i) {
            float lo = acc[i];
            float hi = (i < 64) ? acc[i + 96] : 0.0f;
            float send = bit ? lo : hi;
            float recv = __shfl_xor(send, 1);
            a[i] = (bit ? hi : lo) + recv;
        }
    }
#pragma unroll
    for (int st = 1; st < 6; ++st) {
        const int h = 96 >> st;              // 48,24,12,6,3
        const int bit = (lane >> st) & 1;
#pragma unroll
        for (int i = 0; i < 48; ++i) {
            if (i < h) {
                float send = bit ? a[i] : a[i + h];
                float recv = __shfl_xor(send, 1 << st);
                a[i] = (bit ? a[i + h] : a[i]) + recv;
            }
        }
    }

    // lane owns jo = 3*bitrev6(lane) + {0,1,2}; combine 2 waves via LDS
    const int base = 3 * (__brev((uint32)lane) >> 26);
#pragma unroll
    for (int i = 0; i < 3; ++i) {
        int jo = base + i;
        if (jo < NJO) atomicAdd(&sl[jo], a[i]);
    }
    __syncthreads();

    // ---- fused squash: thread p < 80 handles jo pair (2p, 2p+1) ----
    if (t < 80) {
        float2 sv = *(const float2*)&sl[2 * t];
        float sq = sv.x * sv.x + sv.y * sv.y;
#pragma unroll
        for (int off = 1; off < 8; off <<= 1) sq += __shfl_xor(sq, off, 8);
        float scale = (sq / (1.0f + sq)) * rsqrtf(sq + 1e-8f);
        float vx = sv.x * scale, vy = sv.y * scale;
        if (FINAL) {
            *(float2*)&outp[b * NJO + 2 * t] = make_float2(vx, vy);
        } else {
            float2 va = *(float2*)&vacc[b * NJO + 2 * t];
            va.x += vx; va.y += vy;
            *(float2*)&vacc[b * NJO + 2 * t] = va;
            ((uint32*)vsb)[b * 80 + t] = f2bf(va.x) | (f2bf(va.y) << 16);
        }
    }
}

// ============================================================================
extern "C" void kernel_launch(void* const* d_in, const int* in_sizes, int n_in,
                              void* d_out, int out_size, void* d_ws, size_t ws_size,
                              hipStream_t stream) {
    (void)in_sizes; (void)n_in; (void)out_size; (void)ws_size;

    const float* x = (const float*)d_in[0];  // [B,R,C]
    const float* W = (const float*)d_in[1];  // [R,J,O,C]
    float* out = (float*)d_out;              // [B,J,O,1] fp32

    char* ws = (char*)d_ws;
    const size_t XBYTES = (size_t)NR * NB * NC * 4;   // 18,874,368
    const size_t UBYTES = (size_t)NB * NR * NJO * 2;  // 188,743,680
    float*  xT   = (float*)ws;
    uint32* u    = (uint32*)(ws + XBYTES);
    float*  vacc = (float*)(ws + XBYTES + UBYTES);              // [B,160] fp32
    uint32* vsb  = (uint32*)(vacc + NB * NJO);                  // [B,80] bf16-pairs

    hipMemsetAsync(vacc, 0, (size_t)NB * NJO * sizeof(float), stream);

    xpose_kernel<<<dim3(NR / 16, NB / 64), 256, 0, stream>>>(x, xT);
    uhat_kernel<<<NR, 320, 0, stream>>>(xT, W, u);

    // iter 0: uniform c -> s0 -> v0 (vacc=v0, vsb=bf16(v0))
    pass_kernel<true, false><<<NB, 128, 0, stream>>>(u, vsb, vacc, nullptr);
    // iter 1: b1 = u.v0 -> s1 -> v1 (vacc=v0+v1, vsb updated)
    pass_kernel<false, false><<<NB, 128, 0, stream>>>(u, vsb, vacc, nullptr);
    // iter 2: b2 = u.(v0+v1) -> s2 -> v2 = output
    pass_kernel<false, true><<<NB, 128, 0, stream>>>(u, vsb, nullptr, out);
}